// Round 1
// baseline (1177.004 us; speedup 1.0000x reference)
//
#include <hip/hip_runtime.h>
#include <hip/hip_bf16.h>

#define F 128

// ---------------- Kernel 1: LSTM step on W0 -> evolved W ----------------
// gates = W0 @ w_ih^T + b_ih + b_hh ; i,f,g,o split ; c = sig(i)*tanh(g);
// W = sig(o)*tanh(c).  One block per row r of W0, 512 threads (one per gate col).
__global__ __launch_bounds__(512) void lstm_evolve_kernel(
    const float* __restrict__ W0, const float* __restrict__ w_ih,
    const float* __restrict__ b_ih, const float* __restrict__ b_hh,
    float* __restrict__ W) {
  __shared__ float srow[F];
  __shared__ float sg[4 * F];
  int r = blockIdx.x;
  int t = threadIdx.x;  // 0..511
  if (t < F) srow[t] = W0[r * F + t];
  __syncthreads();
  float acc = 0.f;
  const float* wv = w_ih + (size_t)t * F;
#pragma unroll 8
  for (int k = 0; k < F; k++) acc += srow[k] * wv[k];
  sg[t] = acc + b_ih[t] + b_hh[t];
  __syncthreads();
  if (t < F) {
    float gi = sg[t];
    float gg = sg[t + 2 * F];
    float go = sg[t + 3 * F];
    float si = 1.f / (1.f + expf(-gi));
    float so = 1.f / (1.f + expf(-go));
    float c = si * tanhf(gg);
    W[r * F + t] = so * tanhf(c);
  }
}

// ---------------- Kernel 2: init h=0, deg=1 (self loop) ----------------
__global__ void init_kernel(float* __restrict__ h, float* __restrict__ deg,
                            int n, long long nf4) {
  long long i = (long long)blockIdx.x * blockDim.x + threadIdx.x;
  long long stride = (long long)gridDim.x * blockDim.x;
  float4 z = make_float4(0.f, 0.f, 0.f, 0.f);
  for (long long j = i; j < nf4; j += stride) ((float4*)h)[j] = z;
  for (long long j = i; j < n; j += stride) deg[j] = 1.f;
}

// ---------------- Kernel 3: degree count over targets ----------------
__global__ void deg_kernel(const int* __restrict__ col, float* __restrict__ deg,
                           int e) {
  int i = blockIdx.x * blockDim.x + threadIdx.x;
  if (i < e) atomicAdd(&deg[col[i]], 1.f);
}

// ---------------- Kernel 4: dis = rsqrt(deg) in place ----------------
__global__ void rsqrt_kernel(float* __restrict__ deg, int n) {
  int i = blockIdx.x * blockDim.x + threadIdx.x;
  if (i < n) deg[i] = rsqrtf(deg[i]);
}

// ---------------- Kernel 5: xw = x @ W  (fp32 vector GEMM) ----------------
// 64 rows/block, K chunked by 32 through LDS. Thread: 4 rows x 8 cols acc.
#define KC 32
__global__ __launch_bounds__(256) void xw_kernel(const float* __restrict__ x,
                                                 const float* __restrict__ W,
                                                 float* __restrict__ xw, int n) {
  __shared__ __align__(16) float Ws[KC][F];   // 16 KB
  __shared__ __align__(16) float xT[KC][64];  // 8 KB  [k][local row]
  int t = threadIdx.x;
  int row0 = blockIdx.x * 64;
  int cseg = t & 15;   // 16 col segments of 8
  int rgrp = t >> 4;   // 16 row groups of 4
  float acc[4][8];
#pragma unroll
  for (int i = 0; i < 4; i++)
#pragma unroll
    for (int j = 0; j < 8; j++) acc[i][j] = 0.f;

  for (int k0 = 0; k0 < F; k0 += KC) {
    // load W chunk: KC*F floats = 1024 float4
    for (int idx = t; idx < KC * F / 4; idx += 256) {
      int kk = idx >> 5;
      int c4 = idx & 31;
      ((float4*)&Ws[kk][0])[c4] = ((const float4*)&W[(size_t)(k0 + kk) * F])[c4];
    }
    // load x chunk transposed: 64 rows x KC
    for (int idx = t; idx < 64 * KC / 4; idx += 256) {
      int lr = idx >> 3;
      int k4 = (idx & 7) * 4;
      int gr = row0 + lr;
      float4 v = make_float4(0.f, 0.f, 0.f, 0.f);
      if (gr < n) v = ((const float4*)&x[(size_t)gr * F])[(k0 + k4) >> 2];
      xT[k4 + 0][lr] = v.x;
      xT[k4 + 1][lr] = v.y;
      xT[k4 + 2][lr] = v.z;
      xT[k4 + 3][lr] = v.w;
    }
    __syncthreads();
#pragma unroll
    for (int k = 0; k < KC; k++) {
      float4 xv = *(const float4*)&xT[k][rgrp * 4];
      float4 wa = *(const float4*)&Ws[k][cseg * 8];
      float4 wb = *(const float4*)&Ws[k][cseg * 8 + 4];
      float xs[4] = {xv.x, xv.y, xv.z, xv.w};
      float ww[8] = {wa.x, wa.y, wa.z, wa.w, wb.x, wb.y, wb.z, wb.w};
#pragma unroll
      for (int i = 0; i < 4; i++)
#pragma unroll
        for (int j = 0; j < 8; j++) acc[i][j] = fmaf(xs[i], ww[j], acc[i][j]);
    }
    __syncthreads();
  }
#pragma unroll
  for (int i = 0; i < 4; i++) {
    int gr = row0 + rgrp * 4 + i;
    if (gr < n) {
      float4 o0 = make_float4(acc[i][0], acc[i][1], acc[i][2], acc[i][3]);
      float4 o1 = make_float4(acc[i][4], acc[i][5], acc[i][6], acc[i][7]);
      float4* dst = (float4*)&xw[(size_t)gr * F + cseg * 8];
      dst[0] = o0;
      dst[1] = o1;
    }
  }
}

// ---------------- Kernel 6: edge gather + atomic scatter ----------------
// 32 threads per edge; float4 gather of xw[row], 4 atomics into h[col].
__global__ __launch_bounds__(256) void scatter_kernel(
    const int* __restrict__ row, const int* __restrict__ col,
    const float* __restrict__ dis, const float* __restrict__ xw,
    float* __restrict__ h, int e) {
  int gid = blockIdx.x * 256 + threadIdx.x;
  int eidx = gid >> 5;
  if (eidx >= e) return;
  int q = gid & 31;
  int r = row[eidx];
  int c = col[eidx];
  float nrm = dis[r] * dis[c];
  float4 v = ((const float4*)(xw + (size_t)r * F))[q];
  float* dst = h + (size_t)c * F + q * 4;
  atomicAdd(dst + 0, nrm * v.x);
  atomicAdd(dst + 1, nrm * v.y);
  atomicAdd(dst + 2, nrm * v.z);
  atomicAdd(dst + 3, nrm * v.w);
}

// ---------------- Kernel 7: self-loop + bias + relu + classifier ----------------
// One wave per node; lane handles features lane and lane+64; shuffle reduce.
__global__ __launch_bounds__(256) void final_kernel(
    const float* __restrict__ h, const float* __restrict__ xw,
    const float* __restrict__ dis, const float* __restrict__ gcn_bias,
    const float* __restrict__ Wc, const float* __restrict__ bc,
    float* __restrict__ out, int n) {
  int wave = threadIdx.x >> 6;
  int lane = threadIdx.x & 63;
  int v = blockIdx.x * 4 + wave;
  if (v >= n) return;
  float d = dis[v];
  float sl = d * d;
  float a0 = 0.f, a1 = 0.f;
#pragma unroll
  for (int j = 0; j < 2; j++) {
    int f = lane + j * 64;
    float hv = h[(size_t)v * F + f] + sl * xw[(size_t)v * F + f] + gcn_bias[f];
    hv = fmaxf(hv, 0.f);
    a0 += hv * Wc[f];
    a1 += hv * Wc[F + f];
  }
#pragma unroll
  for (int off = 32; off > 0; off >>= 1) {
    a0 += __shfl_down(a0, off);
    a1 += __shfl_down(a1, off);
  }
  if (lane == 0) {
    out[(size_t)v * 2 + 0] = a0 + bc[0];
    out[(size_t)v * 2 + 1] = a1 + bc[1];
  }
}

extern "C" void kernel_launch(void* const* d_in, const int* in_sizes, int n_in,
                              void* d_out, int out_size, void* d_ws, size_t ws_size,
                              hipStream_t stream) {
  const float* x        = (const float*)d_in[0];
  const float* W0       = (const float*)d_in[1];
  const float* w_ih     = (const float*)d_in[2];
  // d_in[3] = w_hh unused (h0 = 0)
  const float* b_ih     = (const float*)d_in[4];
  const float* b_hh     = (const float*)d_in[5];
  const float* gcn_bias = (const float*)d_in[6];
  const float* Wc       = (const float*)d_in[7];
  const float* bc       = (const float*)d_in[8];
  const int*   ei       = (const int*)d_in[9];

  const int n = in_sizes[0] / F;     // 50000
  const int e = in_sizes[9] / 2;     // 600000
  const int* row = ei;
  const int* col = ei + e;

  float* ws  = (float*)d_ws;
  float* Wev = ws;                          // F*F = 16384 floats
  float* deg = ws + F * F;                  // n floats (becomes dis in place)
  size_t off = (size_t)F * F + (((size_t)n + 15) & ~(size_t)15);
  float* xw = ws + off;                     // n*F floats
  float* h  = xw + (size_t)n * F;           // n*F floats

  // 1. LSTM weight evolution
  lstm_evolve_kernel<<<F, 512, 0, stream>>>(W0, w_ih, b_ih, b_hh, Wev);

  // 2. init h = 0, deg = 1
  long long nf4 = (long long)n * F / 4;
  init_kernel<<<2048, 256, 0, stream>>>(h, deg, n, nf4);

  // 3. in-degree over targets
  deg_kernel<<<(e + 255) / 256, 256, 0, stream>>>(col, deg, e);

  // 4. dis = rsqrt(deg)
  rsqrt_kernel<<<(n + 255) / 256, 256, 0, stream>>>(deg, n);

  // 5. xw = x @ W
  xw_kernel<<<(n + 63) / 64, 256, 0, stream>>>(x, Wev, xw, n);

  // 6. edge messages, atomic scatter
  long long threads = (long long)e * 32;
  int blocks = (int)((threads + 255) / 256);
  scatter_kernel<<<blocks, 256, 0, stream>>>(row, col, deg, xw, h, e);

  // 7. self-loop + bias + relu + classifier
  final_kernel<<<(n + 3) / 4, 256, 0, stream>>>(h, xw, deg, gcn_bias, Wc, bc,
                                                (float*)d_out, n);
}

// Round 2
// 364.334 us; speedup vs baseline: 3.2306x; 3.2306x over previous
//
#include <hip/hip_runtime.h>
#include <hip/hip_bf16.h>

#define F 128

// ---------------- Kernel 1: LSTM step on W0 -> evolved W ----------------
__global__ __launch_bounds__(512) void lstm_evolve_kernel(
    const float* __restrict__ W0, const float* __restrict__ w_ih,
    const float* __restrict__ b_ih, const float* __restrict__ b_hh,
    float* __restrict__ W) {
  __shared__ float srow[F];
  __shared__ float sg[4 * F];
  int r = blockIdx.x;
  int t = threadIdx.x;  // 0..511
  if (t < F) srow[t] = W0[r * F + t];
  __syncthreads();
  float acc = 0.f;
  const float* wv = w_ih + (size_t)t * F;
#pragma unroll 8
  for (int k = 0; k < F; k++) acc += srow[k] * wv[k];
  sg[t] = acc + b_ih[t] + b_hh[t];
  __syncthreads();
  if (t < F) {
    float gi = sg[t];
    float gg = sg[t + 2 * F];
    float go = sg[t + 3 * F];
    float si = 1.f / (1.f + expf(-gi));
    float so = 1.f / (1.f + expf(-go));
    float c = si * tanhf(gg);
    W[r * F + t] = so * tanhf(c);
  }
}

// ---------------- Kernel 2: zero int degree array ----------------
__global__ void zero_deg_kernel(int* __restrict__ deg, int n) {
  int i = blockIdx.x * blockDim.x + threadIdx.x;
  if (i < n) deg[i] = 0;
}

// ---------------- Kernel 3: in-degree count over targets (int atomics) ----
__global__ void deg_kernel(const int* __restrict__ col, int* __restrict__ deg,
                           int e) {
  int i = blockIdx.x * blockDim.x + threadIdx.x;
  if (i < e) atomicAdd(&deg[col[i]], 1);
}

// ---------------- Kernel 4: single-block exclusive scan + dis ----------------
// starts = exclusive_scan(deg); cursor = starts; dis = rsqrt(deg+1).
#define SCAN_T 1024
__global__ __launch_bounds__(SCAN_T) void scan_kernel(
    const int* __restrict__ deg, int* __restrict__ starts,
    int* __restrict__ cursor, float* __restrict__ dis, int n) {
  __shared__ int part[SCAN_T];
  int t = threadIdx.x;
  int chunk = (n + SCAN_T - 1) / SCAN_T;
  int b = t * chunk;
  int eend = b + chunk < n ? b + chunk : n;
  int s = 0;
  for (int i = b; i < eend; i++) s += deg[i];
  part[t] = s;
  __syncthreads();
  for (int off = 1; off < SCAN_T; off <<= 1) {
    int v = (t >= off) ? part[t - off] : 0;
    __syncthreads();
    part[t] += v;
    __syncthreads();
  }
  int run = (t == 0) ? 0 : part[t - 1];
  for (int i = b; i < eend; i++) {
    starts[i] = run;
    cursor[i] = run;
    run += deg[i];
    dis[i] = rsqrtf((float)(deg[i] + 1));  // +1 self loop, always > 0
  }
}

// ---------------- Kernel 5: fill CSR buckets (by target) ----------------
__global__ void fill_kernel(const int* __restrict__ row,
                            const int* __restrict__ col,
                            int* __restrict__ cursor,
                            int* __restrict__ csr_src, int e) {
  int i = blockIdx.x * blockDim.x + threadIdx.x;
  if (i < e) {
    int c = col[i];
    int p = atomicAdd(&cursor[c], 1);
    csr_src[p] = row[i];
  }
}

// ---------------- Kernel 6: xw = x @ W  (fp32 vector GEMM) ----------------
#define KC 32
__global__ __launch_bounds__(256) void xw_kernel(const float* __restrict__ x,
                                                 const float* __restrict__ W,
                                                 float* __restrict__ xw, int n) {
  __shared__ __align__(16) float Ws[KC][F];   // 16 KB
  __shared__ __align__(16) float xT[KC][64];  // 8 KB
  int t = threadIdx.x;
  int row0 = blockIdx.x * 64;
  int cseg = t & 15;
  int rgrp = t >> 4;
  float acc[4][8];
#pragma unroll
  for (int i = 0; i < 4; i++)
#pragma unroll
    for (int j = 0; j < 8; j++) acc[i][j] = 0.f;

  for (int k0 = 0; k0 < F; k0 += KC) {
    for (int idx = t; idx < KC * F / 4; idx += 256) {
      int kk = idx >> 5;
      int c4 = idx & 31;
      ((float4*)&Ws[kk][0])[c4] = ((const float4*)&W[(size_t)(k0 + kk) * F])[c4];
    }
    for (int idx = t; idx < 64 * KC / 4; idx += 256) {
      int lr = idx >> 3;
      int k4 = (idx & 7) * 4;
      int gr = row0 + lr;
      float4 v = make_float4(0.f, 0.f, 0.f, 0.f);
      if (gr < n) v = ((const float4*)&x[(size_t)gr * F])[(k0 + k4) >> 2];
      xT[k4 + 0][lr] = v.x;
      xT[k4 + 1][lr] = v.y;
      xT[k4 + 2][lr] = v.z;
      xT[k4 + 3][lr] = v.w;
    }
    __syncthreads();
#pragma unroll
    for (int k = 0; k < KC; k++) {
      float4 xv = *(const float4*)&xT[k][rgrp * 4];
      float4 wa = *(const float4*)&Ws[k][cseg * 8];
      float4 wb = *(const float4*)&Ws[k][cseg * 8 + 4];
      float xs[4] = {xv.x, xv.y, xv.z, xv.w};
      float ww[8] = {wa.x, wa.y, wa.z, wa.w, wb.x, wb.y, wb.z, wb.w};
#pragma unroll
      for (int i = 0; i < 4; i++)
#pragma unroll
        for (int j = 0; j < 8; j++) acc[i][j] = fmaf(xs[i], ww[j], acc[i][j]);
    }
    __syncthreads();
  }
#pragma unroll
  for (int i = 0; i < 4; i++) {
    int gr = row0 + rgrp * 4 + i;
    if (gr < n) {
      float4 o0 = make_float4(acc[i][0], acc[i][1], acc[i][2], acc[i][3]);
      float4 o1 = make_float4(acc[i][4], acc[i][5], acc[i][6], acc[i][7]);
      float4* dst = (float4*)&xw[(size_t)gr * F + cseg * 8];
      dst[0] = o0;
      dst[1] = o1;
    }
  }
}

// ---------------- Kernel 7: pull aggregation + epilogue (fused) ----------------
// One wave per target node. Lane owns features [2*lane, 2*lane+1] (float2
// => 512 B coalesced gather per source row). Register accumulate, then
// bias + relu + 128->2 classifier with shuffle reduction.
__global__ __launch_bounds__(256) void agg_kernel(
    const int* __restrict__ starts, const int* __restrict__ deg,
    const int* __restrict__ csr_src, const float* __restrict__ dis,
    const float* __restrict__ xw, const float* __restrict__ gcn_bias,
    const float* __restrict__ Wc, const float* __restrict__ bc,
    float* __restrict__ out, int n) {
  int wave = threadIdx.x >> 6;
  int lane = threadIdx.x & 63;
  int v = blockIdx.x * 4 + wave;
  if (v >= n) return;
  float dv = dis[v];
  const float2* xw2 = (const float2*)xw;
  float ax, ay;
  {
    float2 xv = xw2[(size_t)v * 64 + lane];  // self loop
    float sl = dv * dv;
    ax = sl * xv.x;
    ay = sl * xv.y;
  }
  int b = starts[v];
  int eend = b + deg[v];
  int j = b;
  for (; j + 4 <= eend; j += 4) {
    int s0 = csr_src[j + 0];
    int s1 = csr_src[j + 1];
    int s2 = csr_src[j + 2];
    int s3 = csr_src[j + 3];
    float n0 = dis[s0] * dv;
    float n1 = dis[s1] * dv;
    float n2 = dis[s2] * dv;
    float n3 = dis[s3] * dv;
    float2 v0 = xw2[(size_t)s0 * 64 + lane];
    float2 v1 = xw2[(size_t)s1 * 64 + lane];
    float2 v2 = xw2[(size_t)s2 * 64 + lane];
    float2 v3 = xw2[(size_t)s3 * 64 + lane];
    ax = fmaf(n0, v0.x, ax); ay = fmaf(n0, v0.y, ay);
    ax = fmaf(n1, v1.x, ax); ay = fmaf(n1, v1.y, ay);
    ax = fmaf(n2, v2.x, ax); ay = fmaf(n2, v2.y, ay);
    ax = fmaf(n3, v3.x, ax); ay = fmaf(n3, v3.y, ay);
  }
  for (; j < eend; j++) {
    int s = csr_src[j];
    float nr = dis[s] * dv;
    float2 vv = xw2[(size_t)s * 64 + lane];
    ax = fmaf(nr, vv.x, ax);
    ay = fmaf(nr, vv.y, ay);
  }
  int f0 = lane * 2;
  float h0 = fmaxf(ax + gcn_bias[f0], 0.f);
  float h1 = fmaxf(ay + gcn_bias[f0 + 1], 0.f);
  float a0 = h0 * Wc[f0] + h1 * Wc[f0 + 1];
  float a1 = h0 * Wc[F + f0] + h1 * Wc[F + f0 + 1];
#pragma unroll
  for (int off = 32; off > 0; off >>= 1) {
    a0 += __shfl_down(a0, off);
    a1 += __shfl_down(a1, off);
  }
  if (lane == 0) {
    out[(size_t)v * 2 + 0] = a0 + bc[0];
    out[(size_t)v * 2 + 1] = a1 + bc[1];
  }
}

extern "C" void kernel_launch(void* const* d_in, const int* in_sizes, int n_in,
                              void* d_out, int out_size, void* d_ws, size_t ws_size,
                              hipStream_t stream) {
  const float* x        = (const float*)d_in[0];
  const float* W0       = (const float*)d_in[1];
  const float* w_ih     = (const float*)d_in[2];
  // d_in[3] = w_hh unused (h0 = 0)
  const float* b_ih     = (const float*)d_in[4];
  const float* b_hh     = (const float*)d_in[5];
  const float* gcn_bias = (const float*)d_in[6];
  const float* Wc       = (const float*)d_in[7];
  const float* bc       = (const float*)d_in[8];
  const int*   ei       = (const int*)d_in[9];

  const int n = in_sizes[0] / F;   // 50000
  const int e = in_sizes[9] / 2;   // 600000
  const int* row = ei;
  const int* col = ei + e;

  // workspace layout
  char* wsb = (char*)d_ws;
  float* Wev    = (float*)wsb;                  wsb += (size_t)F * F * 4;
  int*   deg    = (int*)wsb;                    wsb += (size_t)n * 4;
  int*   starts = (int*)wsb;                    wsb += (size_t)n * 4;
  int*   cursor = (int*)wsb;                    wsb += (size_t)n * 4;
  float* dis    = (float*)wsb;                  wsb += (size_t)n * 4;
  int*   csr    = (int*)wsb;                    wsb += (size_t)e * 4;
  float* xw     = (float*)wsb;

  // 1. LSTM weight evolution (independent of graph work)
  lstm_evolve_kernel<<<F, 512, 0, stream>>>(W0, w_ih, b_ih, b_hh, Wev);

  // 2. zero degrees
  zero_deg_kernel<<<(n + 255) / 256, 256, 0, stream>>>(deg, n);

  // 3. in-degree over targets
  deg_kernel<<<(e + 255) / 256, 256, 0, stream>>>(col, deg, e);

  // 4. exclusive scan + cursor copy + dis = rsqrt(deg+1)
  scan_kernel<<<1, SCAN_T, 0, stream>>>(deg, starts, cursor, dis, n);

  // 5. CSR bucket fill
  fill_kernel<<<(e + 255) / 256, 256, 0, stream>>>(row, col, cursor, csr, e);

  // 6. xw = x @ W
  xw_kernel<<<(n + 63) / 64, 256, 0, stream>>>(x, Wev, xw, n);

  // 7. fused pull-aggregation + bias + relu + classifier
  agg_kernel<<<(n + 3) / 4, 256, 0, stream>>>(starts, deg, csr, dis, xw,
                                              gcn_bias, Wc, bc,
                                              (float*)d_out, n);
}

// Round 3
// 240.748 us; speedup vs baseline: 4.8890x; 1.5133x over previous
//
#include <hip/hip_runtime.h>
#include <hip/hip_bf16.h>

#define F 128

// ---------------- Kernel 1: LSTM step on W0 -> evolved W ----------------
__global__ __launch_bounds__(512) void lstm_evolve_kernel(
    const float* __restrict__ W0, const float* __restrict__ w_ih,
    const float* __restrict__ b_ih, const float* __restrict__ b_hh,
    float* __restrict__ W) {
  __shared__ float srow[F];
  __shared__ float sg[4 * F];
  int r = blockIdx.x;
  int t = threadIdx.x;  // 0..511
  if (t < F) srow[t] = W0[r * F + t];
  __syncthreads();
  float acc = 0.f;
  const float* wv = w_ih + (size_t)t * F;
#pragma unroll 8
  for (int k = 0; k < F; k++) acc += srow[k] * wv[k];
  sg[t] = acc + b_ih[t] + b_hh[t];
  __syncthreads();
  if (t < F) {
    float gi = sg[t];
    float gg = sg[t + 2 * F];
    float go = sg[t + 3 * F];
    float si = 1.f / (1.f + expf(-gi));
    float so = 1.f / (1.f + expf(-go));
    float c = si * tanhf(gg);
    W[r * F + t] = so * tanhf(c);
  }
}

// ---------------- Kernel 2: zero int degree array ----------------
__global__ void zero_deg_kernel(int* __restrict__ deg, int n) {
  int i = blockIdx.x * blockDim.x + threadIdx.x;
  if (i < n) deg[i] = 0;
}

// ---------------- Kernel 3: in-degree count over targets (int atomics) ----
__global__ void deg_kernel(const int* __restrict__ col, int* __restrict__ deg,
                           int e) {
  int i = blockIdx.x * blockDim.x + threadIdx.x;
  if (i < e) atomicAdd(&deg[col[i]], 1);
}

// ---------------- Hierarchical exclusive scan (n <= 64*1024) --------------
// Phase A: per-block (1024 elems) sum -> bsum[64]
__global__ __launch_bounds__(256) void scanA_kernel(const int* __restrict__ deg,
                                                    int* __restrict__ bsum,
                                                    int n) {
  int t = threadIdx.x, b = blockIdx.x;
  int base = b * 1024 + t * 4;
  int s = 0;
#pragma unroll
  for (int i = 0; i < 4; i++) {
    int idx = base + i;
    if (idx < n) s += deg[idx];
  }
#pragma unroll
  for (int off = 32; off > 0; off >>= 1) s += __shfl_down(s, off);
  __shared__ int wsum[4];
  if ((t & 63) == 0) wsum[t >> 6] = s;
  __syncthreads();
  if (t == 0) bsum[b] = wsum[0] + wsum[1] + wsum[2] + wsum[3];
}

// Phase B: one wave, exclusive scan of 64 block sums in place
__global__ void scanB_kernel(int* __restrict__ bsum) {
  int lane = threadIdx.x;  // 0..63
  int v = bsum[lane];
  int inc = v;
#pragma unroll
  for (int off = 1; off < 64; off <<= 1) {
    int u = __shfl_up(inc, off);
    if (lane >= off) inc += u;
  }
  bsum[lane] = inc - v;  // exclusive prefix
}

// Phase C: block-local exclusive scan + block prefix; write starts/cursor/dis
__global__ __launch_bounds__(256) void scanC_kernel(
    const int* __restrict__ deg, const int* __restrict__ bsum,
    int* __restrict__ starts, int* __restrict__ cursor,
    float* __restrict__ dis, int n) {
  int t = threadIdx.x, b = blockIdx.x;
  int lane = t & 63, wave = t >> 6;
  int base = b * 1024 + t * 4;
  int v[4];
  int s = 0;
#pragma unroll
  for (int i = 0; i < 4; i++) {
    int idx = base + i;
    v[i] = (idx < n) ? deg[idx] : 0;
    s += v[i];
  }
  int inc = s;
#pragma unroll
  for (int off = 1; off < 64; off <<= 1) {
    int u = __shfl_up(inc, off);
    if (lane >= off) inc += u;
  }
  __shared__ int wsum[4];
  if (lane == 63) wsum[wave] = inc;
  __syncthreads();
  int woff = 0;
  for (int w = 0; w < wave; w++) woff += wsum[w];
  int excl = inc - s + woff + bsum[b];
#pragma unroll
  for (int i = 0; i < 4; i++) {
    int idx = base + i;
    if (idx < n) {
      starts[idx] = excl;
      cursor[idx] = excl;
      dis[idx] = rsqrtf((float)(v[i] + 1));  // +1 self loop, always > 0
    }
    excl += v[i];
  }
}

// ---------------- Kernel 5: fill CSR buckets (by target) ----------------
__global__ void fill_kernel(const int* __restrict__ row,
                            const int* __restrict__ col,
                            int* __restrict__ cursor,
                            int* __restrict__ csr_src, int e) {
  int i = blockIdx.x * blockDim.x + threadIdx.x;
  if (i < e) {
    int c = col[i];
    int p = atomicAdd(&cursor[c], 1);
    csr_src[p] = row[i];
  }
}

// ---------------- Kernel 6: xw = x @ W  (fp32 vector GEMM) ----------------
#define KC 32
__global__ __launch_bounds__(256) void xw_kernel(const float* __restrict__ x,
                                                 const float* __restrict__ W,
                                                 float* __restrict__ xw, int n) {
  __shared__ __align__(16) float Ws[KC][F];   // 16 KB
  __shared__ __align__(16) float xT[KC][64];  // 8 KB
  int t = threadIdx.x;
  int row0 = blockIdx.x * 64;
  int cseg = t & 15;
  int rgrp = t >> 4;
  float acc[4][8];
#pragma unroll
  for (int i = 0; i < 4; i++)
#pragma unroll
    for (int j = 0; j < 8; j++) acc[i][j] = 0.f;

  for (int k0 = 0; k0 < F; k0 += KC) {
    for (int idx = t; idx < KC * F / 4; idx += 256) {
      int kk = idx >> 5;
      int c4 = idx & 31;
      ((float4*)&Ws[kk][0])[c4] = ((const float4*)&W[(size_t)(k0 + kk) * F])[c4];
    }
    for (int idx = t; idx < 64 * KC / 4; idx += 256) {
      int lr = idx >> 3;
      int k4 = (idx & 7) * 4;
      int gr = row0 + lr;
      float4 v = make_float4(0.f, 0.f, 0.f, 0.f);
      if (gr < n) v = ((const float4*)&x[(size_t)gr * F])[(k0 + k4) >> 2];
      xT[k4 + 0][lr] = v.x;
      xT[k4 + 1][lr] = v.y;
      xT[k4 + 2][lr] = v.z;
      xT[k4 + 3][lr] = v.w;
    }
    __syncthreads();
#pragma unroll
    for (int k = 0; k < KC; k++) {
      float4 xv = *(const float4*)&xT[k][rgrp * 4];
      float4 wa = *(const float4*)&Ws[k][cseg * 8];
      float4 wb = *(const float4*)&Ws[k][cseg * 8 + 4];
      float xs[4] = {xv.x, xv.y, xv.z, xv.w};
      float ww[8] = {wa.x, wa.y, wa.z, wa.w, wb.x, wb.y, wb.z, wb.w};
#pragma unroll
      for (int i = 0; i < 4; i++)
#pragma unroll
        for (int j = 0; j < 8; j++) acc[i][j] = fmaf(xs[i], ww[j], acc[i][j]);
    }
    __syncthreads();
  }
#pragma unroll
  for (int i = 0; i < 4; i++) {
    int gr = row0 + rgrp * 4 + i;
    if (gr < n) {
      float4 o0 = make_float4(acc[i][0], acc[i][1], acc[i][2], acc[i][3]);
      float4 o1 = make_float4(acc[i][4], acc[i][5], acc[i][6], acc[i][7]);
      float4* dst = (float4*)&xw[(size_t)gr * F + cseg * 8];
      dst[0] = o0;
      dst[1] = o1;
    }
  }
}

// ---------------- Kernel 7: pull aggregation + epilogue (fused) ----------------
__global__ __launch_bounds__(256) void agg_kernel(
    const int* __restrict__ starts, const int* __restrict__ deg,
    const int* __restrict__ csr_src, const float* __restrict__ dis,
    const float* __restrict__ xw, const float* __restrict__ gcn_bias,
    const float* __restrict__ Wc, const float* __restrict__ bc,
    float* __restrict__ out, int n) {
  int wave = threadIdx.x >> 6;
  int lane = threadIdx.x & 63;
  int v = blockIdx.x * 4 + wave;
  if (v >= n) return;
  float dv = dis[v];
  const float2* xw2 = (const float2*)xw;
  float ax, ay;
  {
    float2 xv = xw2[(size_t)v * 64 + lane];  // self loop
    float sl = dv * dv;
    ax = sl * xv.x;
    ay = sl * xv.y;
  }
  int b = starts[v];
  int eend = b + deg[v];
  int j = b;
  for (; j + 4 <= eend; j += 4) {
    int s0 = csr_src[j + 0];
    int s1 = csr_src[j + 1];
    int s2 = csr_src[j + 2];
    int s3 = csr_src[j + 3];
    float n0 = dis[s0] * dv;
    float n1 = dis[s1] * dv;
    float n2 = dis[s2] * dv;
    float n3 = dis[s3] * dv;
    float2 v0 = xw2[(size_t)s0 * 64 + lane];
    float2 v1 = xw2[(size_t)s1 * 64 + lane];
    float2 v2 = xw2[(size_t)s2 * 64 + lane];
    float2 v3 = xw2[(size_t)s3 * 64 + lane];
    ax = fmaf(n0, v0.x, ax); ay = fmaf(n0, v0.y, ay);
    ax = fmaf(n1, v1.x, ax); ay = fmaf(n1, v1.y, ay);
    ax = fmaf(n2, v2.x, ax); ay = fmaf(n2, v2.y, ay);
    ax = fmaf(n3, v3.x, ax); ay = fmaf(n3, v3.y, ay);
  }
  for (; j < eend; j++) {
    int s = csr_src[j];
    float nr = dis[s] * dv;
    float2 vv = xw2[(size_t)s * 64 + lane];
    ax = fmaf(nr, vv.x, ax);
    ay = fmaf(nr, vv.y, ay);
  }
  int f0 = lane * 2;
  float h0 = fmaxf(ax + gcn_bias[f0], 0.f);
  float h1 = fmaxf(ay + gcn_bias[f0 + 1], 0.f);
  float a0 = h0 * Wc[f0] + h1 * Wc[f0 + 1];
  float a1 = h0 * Wc[F + f0] + h1 * Wc[F + f0 + 1];
#pragma unroll
  for (int off = 32; off > 0; off >>= 1) {
    a0 += __shfl_down(a0, off);
    a1 += __shfl_down(a1, off);
  }
  if (lane == 0) {
    out[(size_t)v * 2 + 0] = a0 + bc[0];
    out[(size_t)v * 2 + 1] = a1 + bc[1];
  }
}

extern "C" void kernel_launch(void* const* d_in, const int* in_sizes, int n_in,
                              void* d_out, int out_size, void* d_ws, size_t ws_size,
                              hipStream_t stream) {
  const float* x        = (const float*)d_in[0];
  const float* W0       = (const float*)d_in[1];
  const float* w_ih     = (const float*)d_in[2];
  // d_in[3] = w_hh unused (h0 = 0)
  const float* b_ih     = (const float*)d_in[4];
  const float* b_hh     = (const float*)d_in[5];
  const float* gcn_bias = (const float*)d_in[6];
  const float* Wc       = (const float*)d_in[7];
  const float* bc       = (const float*)d_in[8];
  const int*   ei       = (const int*)d_in[9];

  const int n = in_sizes[0] / F;   // 50000
  const int e = in_sizes[9] / 2;   // 600000
  const int* row = ei;
  const int* col = ei + e;

  // workspace layout
  char* wsb = (char*)d_ws;
  float* Wev    = (float*)wsb;                  wsb += (size_t)F * F * 4;
  int*   deg    = (int*)wsb;                    wsb += (size_t)n * 4;
  int*   starts = (int*)wsb;                    wsb += (size_t)n * 4;
  int*   cursor = (int*)wsb;                    wsb += (size_t)n * 4;
  float* dis    = (float*)wsb;                  wsb += (size_t)n * 4;
  int*   bsum   = (int*)wsb;                    wsb += 64 * 4;
  int*   csr    = (int*)wsb;                    wsb += (size_t)e * 4;
  float* xw     = (float*)wsb;

  const int scan_blocks = 64;  // covers 64*1024 = 65536 >= n

  // 1. LSTM weight evolution (independent of graph work)
  lstm_evolve_kernel<<<F, 512, 0, stream>>>(W0, w_ih, b_ih, b_hh, Wev);

  // 2. zero degrees
  zero_deg_kernel<<<(n + 255) / 256, 256, 0, stream>>>(deg, n);

  // 3. in-degree over targets
  deg_kernel<<<(e + 255) / 256, 256, 0, stream>>>(col, deg, e);

  // 4. hierarchical exclusive scan + cursor + dis = rsqrt(deg+1)
  scanA_kernel<<<scan_blocks, 256, 0, stream>>>(deg, bsum, n);
  scanB_kernel<<<1, 64, 0, stream>>>(bsum);
  scanC_kernel<<<scan_blocks, 256, 0, stream>>>(deg, bsum, starts, cursor, dis, n);

  // 5. CSR bucket fill
  fill_kernel<<<(e + 255) / 256, 256, 0, stream>>>(row, col, cursor, csr, e);

  // 6. xw = x @ W
  xw_kernel<<<(n + 63) / 64, 256, 0, stream>>>(x, Wev, xw, n);

  // 7. fused pull-aggregation + bias + relu + classifier
  agg_kernel<<<(n + 3) / 4, 256, 0, stream>>>(starts, deg, csr, dis, xw,
                                              gcn_bias, Wc, bc,
                                              (float*)d_out, n);
}

// Round 4
// 233.569 us; speedup vs baseline: 5.0392x; 1.0307x over previous
//
#include <hip/hip_runtime.h>
#include <hip/hip_bf16.h>

#define F 128

// ---- bf16 helpers (RNE via bit trick) ----
static __device__ __forceinline__ unsigned int f2bfbits(float f) {
  unsigned int u = __float_as_uint(f);
  return (u + 0x7fffu + ((u >> 16) & 1u)) >> 16;
}
static __device__ __forceinline__ unsigned int pack2bf(float a, float b) {
  return f2bfbits(a) | (f2bfbits(b) << 16);
}

// ---------------- Kernel 1: LSTM step on W0 -> evolved W ----------------
// 4 rows per block, 32 blocks. gates = W0 @ w_ih^T + b_ih + b_hh.
#define LROWS 4
__global__ __launch_bounds__(512) void lstm_evolve_kernel(
    const float* __restrict__ W0, const float* __restrict__ w_ih,
    const float* __restrict__ b_ih, const float* __restrict__ b_hh,
    float* __restrict__ W) {
  __shared__ __align__(16) float srow[LROWS][F];
  __shared__ float sg[LROWS][4 * F];
  int r0 = blockIdx.x * LROWS;
  int t = threadIdx.x;  // 0..511
  {
    int rr = t >> 7, cc = t & 127;
    srow[rr][cc] = W0[(size_t)(r0 + rr) * F + cc];
  }
  __syncthreads();
  float acc[LROWS] = {0.f, 0.f, 0.f, 0.f};
  const float4* wv4 = (const float4*)(w_ih + (size_t)t * F);
#pragma unroll 4
  for (int k4 = 0; k4 < F / 4; k4++) {
    float4 w = wv4[k4];
#pragma unroll
    for (int i = 0; i < LROWS; i++) {
      float4 s = *(const float4*)&srow[i][k4 * 4];
      acc[i] = fmaf(s.x, w.x, fmaf(s.y, w.y, fmaf(s.z, w.z, fmaf(s.w, w.w, acc[i]))));
    }
  }
  float bias = b_ih[t] + b_hh[t];
#pragma unroll
  for (int i = 0; i < LROWS; i++) sg[i][t] = acc[i] + bias;
  __syncthreads();
  {
    int rr = t >> 7, c = t & 127;
    float gi = sg[rr][c];
    float gg = sg[rr][c + 2 * F];
    float go = sg[rr][c + 3 * F];
    float si = 1.f / (1.f + expf(-gi));
    float so = 1.f / (1.f + expf(-go));
    float cc2 = si * tanhf(gg);
    W[(size_t)(r0 + rr) * F + c] = so * tanhf(cc2);
  }
}

// ---------------- Kernel 3: in-degree count over targets (int atomics) ----
__global__ void deg_kernel(const int* __restrict__ col, int* __restrict__ deg,
                           int e) {
  int i = blockIdx.x * blockDim.x + threadIdx.x;
  if (i < e) atomicAdd(&deg[col[i]], 1);
}

// ---------------- Hierarchical exclusive scan (n <= 64*1024) --------------
// Phase A: per-block (1024 elems) sum -> bsum[64]
__global__ __launch_bounds__(256) void scanA_kernel(const int* __restrict__ deg,
                                                    int* __restrict__ bsum,
                                                    int n) {
  int t = threadIdx.x, b = blockIdx.x;
  int base = b * 1024 + t * 4;
  int s = 0;
#pragma unroll
  for (int i = 0; i < 4; i++) {
    int idx = base + i;
    if (idx < n) s += deg[idx];
  }
#pragma unroll
  for (int off = 32; off > 0; off >>= 1) s += __shfl_down(s, off);
  __shared__ int wsum[4];
  if ((t & 63) == 0) wsum[t >> 6] = s;
  __syncthreads();
  if (t == 0) bsum[b] = wsum[0] + wsum[1] + wsum[2] + wsum[3];
}

// Phase C: block prefix computed in-kernel from bsum (no separate phase B),
// block-local exclusive scan; write starts/cursor/dis.
__global__ __launch_bounds__(256) void scanC_kernel(
    const int* __restrict__ deg, const int* __restrict__ bsum,
    int* __restrict__ starts, int* __restrict__ cursor,
    float* __restrict__ dis, int n) {
  int t = threadIdx.x, b = blockIdx.x;
  int lane = t & 63, wave = t >> 6;
  __shared__ int wsum[4];
  __shared__ int bpre;
  if (wave == 0) {
    int v = (lane < b) ? bsum[lane] : 0;
#pragma unroll
    for (int off = 32; off > 0; off >>= 1) v += __shfl_down(v, off);
    if (lane == 0) bpre = v;
  }
  int base = b * 1024 + t * 4;
  int v[4];
  int s = 0;
#pragma unroll
  for (int i = 0; i < 4; i++) {
    int idx = base + i;
    v[i] = (idx < n) ? deg[idx] : 0;
    s += v[i];
  }
  int inc = s;
#pragma unroll
  for (int off = 1; off < 64; off <<= 1) {
    int u = __shfl_up(inc, off);
    if (lane >= off) inc += u;
  }
  if (lane == 63) wsum[wave] = inc;
  __syncthreads();
  int woff = 0;
  for (int w = 0; w < wave; w++) woff += wsum[w];
  int excl = inc - s + woff + bpre;
#pragma unroll
  for (int i = 0; i < 4; i++) {
    int idx = base + i;
    if (idx < n) {
      starts[idx] = excl;
      cursor[idx] = excl;
      dis[idx] = rsqrtf((float)(v[i] + 1));  // +1 self loop, always > 0
    }
    excl += v[i];
  }
}

// ---------------- Kernel 5: fill CSR buckets (by target) ----------------
__global__ void fill_kernel(const int* __restrict__ row,
                            const int* __restrict__ col,
                            int* __restrict__ cursor,
                            int* __restrict__ csr_src, int e) {
  int i = blockIdx.x * blockDim.x + threadIdx.x;
  if (i < e) {
    int c = col[i];
    int p = atomicAdd(&cursor[c], 1);
    csr_src[p] = row[i];
  }
}

// ---------------- Kernel 6: xw = x @ W  (fp32 VALU GEMM, bf16 output) ------
#define KC 32
__global__ __launch_bounds__(256) void xw_kernel(const float* __restrict__ x,
                                                 const float* __restrict__ W,
                                                 unsigned int* __restrict__ xwb,
                                                 int n) {
  __shared__ __align__(16) float Ws[KC][F];   // 16 KB
  __shared__ __align__(16) float xT[KC][64];  // 8 KB
  int t = threadIdx.x;
  int row0 = blockIdx.x * 64;
  int cseg = t & 15;
  int rgrp = t >> 4;
  float acc[4][8];
#pragma unroll
  for (int i = 0; i < 4; i++)
#pragma unroll
    for (int j = 0; j < 8; j++) acc[i][j] = 0.f;

  for (int k0 = 0; k0 < F; k0 += KC) {
    for (int idx = t; idx < KC * F / 4; idx += 256) {
      int kk = idx >> 5;
      int c4 = idx & 31;
      ((float4*)&Ws[kk][0])[c4] = ((const float4*)&W[(size_t)(k0 + kk) * F])[c4];
    }
    for (int idx = t; idx < 64 * KC / 4; idx += 256) {
      int lr = idx >> 3;
      int k4 = (idx & 7) * 4;
      int gr = row0 + lr;
      float4 v = make_float4(0.f, 0.f, 0.f, 0.f);
      if (gr < n) v = ((const float4*)&x[(size_t)gr * F])[(k0 + k4) >> 2];
      xT[k4 + 0][lr] = v.x;
      xT[k4 + 1][lr] = v.y;
      xT[k4 + 2][lr] = v.z;
      xT[k4 + 3][lr] = v.w;
    }
    __syncthreads();
#pragma unroll
    for (int k = 0; k < KC; k++) {
      float4 xv = *(const float4*)&xT[k][rgrp * 4];
      float4 wa = *(const float4*)&Ws[k][cseg * 8];
      float4 wb = *(const float4*)&Ws[k][cseg * 8 + 4];
      float xs[4] = {xv.x, xv.y, xv.z, xv.w};
      float ww[8] = {wa.x, wa.y, wa.z, wa.w, wb.x, wb.y, wb.z, wb.w};
#pragma unroll
      for (int i = 0; i < 4; i++)
#pragma unroll
        for (int j = 0; j < 8; j++) acc[i][j] = fmaf(xs[i], ww[j], acc[i][j]);
    }
    __syncthreads();
  }
#pragma unroll
  for (int i = 0; i < 4; i++) {
    int gr = row0 + rgrp * 4 + i;
    if (gr < n) {
      uint4 o;
      o.x = pack2bf(acc[i][0], acc[i][1]);
      o.y = pack2bf(acc[i][2], acc[i][3]);
      o.z = pack2bf(acc[i][4], acc[i][5]);
      o.w = pack2bf(acc[i][6], acc[i][7]);
      ((uint4*)(xwb + (size_t)gr * 64))[cseg] = o;
    }
  }
}

// ---------------- Kernel 7: pull aggregation + epilogue (fused, bf16 gather) --
// One wave per target node. Lane owns features [2*lane, 2*lane+1] packed in
// one uint of the bf16 xw row (256 B coalesced gather per source row).
__global__ __launch_bounds__(256) void agg_kernel(
    const int* __restrict__ starts, const int* __restrict__ deg,
    const int* __restrict__ csr_src, const float* __restrict__ dis,
    const unsigned int* __restrict__ xwb, const float* __restrict__ gcn_bias,
    const float* __restrict__ Wc, const float* __restrict__ bc,
    float* __restrict__ out, int n) {
  int wave = threadIdx.x >> 6;
  int lane = threadIdx.x & 63;
  int v = blockIdx.x * 4 + wave;
  if (v >= n) return;
  float dv = dis[v];
  float ax, ay;
  {
    unsigned int u = xwb[(size_t)v * 64 + lane];  // self loop
    float sl = dv * dv;
    ax = sl * __uint_as_float(u << 16);
    ay = sl * __uint_as_float(u & 0xffff0000u);
  }
  int b = starts[v];
  int eend = b + deg[v];
  int j = b;
  for (; j + 8 <= eend; j += 8) {
    int s[8];
    float nr[8];
    unsigned int u[8];
#pragma unroll
    for (int q = 0; q < 8; q++) s[q] = csr_src[j + q];
#pragma unroll
    for (int q = 0; q < 8; q++) nr[q] = dis[s[q]] * dv;
#pragma unroll
    for (int q = 0; q < 8; q++) u[q] = xwb[(size_t)s[q] * 64 + lane];
#pragma unroll
    for (int q = 0; q < 8; q++) {
      ax = fmaf(nr[q], __uint_as_float(u[q] << 16), ax);
      ay = fmaf(nr[q], __uint_as_float(u[q] & 0xffff0000u), ay);
    }
  }
  for (; j < eend; j++) {
    int s = csr_src[j];
    float nr = dis[s] * dv;
    unsigned int u = xwb[(size_t)s * 64 + lane];
    ax = fmaf(nr, __uint_as_float(u << 16), ax);
    ay = fmaf(nr, __uint_as_float(u & 0xffff0000u), ay);
  }
  int f0 = lane * 2;
  float h0 = fmaxf(ax + gcn_bias[f0], 0.f);
  float h1 = fmaxf(ay + gcn_bias[f0 + 1], 0.f);
  float a0 = h0 * Wc[f0] + h1 * Wc[f0 + 1];
  float a1 = h0 * Wc[F + f0] + h1 * Wc[F + f0 + 1];
#pragma unroll
  for (int off = 32; off > 0; off >>= 1) {
    a0 += __shfl_down(a0, off);
    a1 += __shfl_down(a1, off);
  }
  if (lane == 0) {
    out[(size_t)v * 2 + 0] = a0 + bc[0];
    out[(size_t)v * 2 + 1] = a1 + bc[1];
  }
}

extern "C" void kernel_launch(void* const* d_in, const int* in_sizes, int n_in,
                              void* d_out, int out_size, void* d_ws, size_t ws_size,
                              hipStream_t stream) {
  const float* x        = (const float*)d_in[0];
  const float* W0       = (const float*)d_in[1];
  const float* w_ih     = (const float*)d_in[2];
  // d_in[3] = w_hh unused (h0 = 0)
  const float* b_ih     = (const float*)d_in[4];
  const float* b_hh     = (const float*)d_in[5];
  const float* gcn_bias = (const float*)d_in[6];
  const float* Wc       = (const float*)d_in[7];
  const float* bc       = (const float*)d_in[8];
  const int*   ei       = (const int*)d_in[9];

  const int n = in_sizes[0] / F;   // 50000
  const int e = in_sizes[9] / 2;   // 600000
  const int* row = ei;
  const int* col = ei + e;

  // workspace layout
  char* wsb = (char*)d_ws;
  float*        Wev    = (float*)wsb;          wsb += (size_t)F * F * 4;
  int*          deg    = (int*)wsb;            wsb += (size_t)n * 4;
  int*          starts = (int*)wsb;            wsb += (size_t)n * 4;
  int*          cursor = (int*)wsb;            wsb += (size_t)n * 4;
  float*        dis    = (float*)wsb;          wsb += (size_t)n * 4;
  int*          bsum   = (int*)wsb;            wsb += 64 * 4;
  int*          csr    = (int*)wsb;            wsb += (size_t)e * 4;
  unsigned int* xwb    = (unsigned int*)wsb;   // n*64 uints (bf16 xw)

  const int scan_blocks = 64;  // covers 64*1024 = 65536 >= n

  // 1. zero degrees (async memset is graph-capturable)
  hipMemsetAsync(deg, 0, (size_t)n * sizeof(int), stream);

  // 2. LSTM weight evolution (independent of graph work)
  lstm_evolve_kernel<<<F / LROWS, 512, 0, stream>>>(W0, w_ih, b_ih, b_hh, Wev);

  // 3. in-degree over targets
  deg_kernel<<<(e + 255) / 256, 256, 0, stream>>>(col, deg, e);

  // 4. hierarchical exclusive scan + cursor + dis = rsqrt(deg+1)
  scanA_kernel<<<scan_blocks, 256, 0, stream>>>(deg, bsum, n);
  scanC_kernel<<<scan_blocks, 256, 0, stream>>>(deg, bsum, starts, cursor, dis, n);

  // 5. CSR bucket fill
  fill_kernel<<<(e + 255) / 256, 256, 0, stream>>>(row, col, cursor, csr, e);

  // 6. xw = x @ W (fp32 compute, bf16 store)
  xw_kernel<<<(n + 63) / 64, 256, 0, stream>>>(x, Wev, xwb, n);

  // 7. fused pull-aggregation + bias + relu + classifier (bf16 gather)
  agg_kernel<<<(n + 3) / 4, 256, 0, stream>>>(starts, deg, csr, dis, xwb,
                                              gcn_bias, Wc, bc,
                                              (float*)d_out, n);
}

// Round 5
// 219.821 us; speedup vs baseline: 5.3544x; 1.0625x over previous
//
#include <hip/hip_runtime.h>
#include <hip/hip_bf16.h>

#define F 128

typedef __bf16 bf16x8 __attribute__((ext_vector_type(8)));
typedef float f32x4 __attribute__((ext_vector_type(4)));

// ---- bf16 helpers (RNE via bit trick) ----
static __device__ __forceinline__ unsigned int f2bfbits(float f) {
  unsigned int u = __float_as_uint(f);
  return (u + 0x7fffu + ((u >> 16) & 1u)) >> 16;
}
static __device__ __forceinline__ unsigned int pack2bf(float a, float b) {
  return f2bfbits(a) | (f2bfbits(b) << 16);
}

// ---------------- Kernel 1: LSTM step on W0 -> evolved W (bf16, transposed) --
// 4 rows per block, 32 blocks. gates = W0 @ w_ih^T + b_ih + b_hh.
// Output: Wt[n][k] = bf16(W[k][n])  (transposed for MFMA B-fragment reads).
#define LROWS 4
__global__ __launch_bounds__(512) void lstm_evolve_kernel(
    const float* __restrict__ W0, const float* __restrict__ w_ih,
    const float* __restrict__ b_ih, const float* __restrict__ b_hh,
    unsigned short* __restrict__ Wt) {
  __shared__ __align__(16) float srow[LROWS][F];
  __shared__ float sg[LROWS][4 * F];
  int r0 = blockIdx.x * LROWS;
  int t = threadIdx.x;  // 0..511
  {
    int rr = t >> 7, cc = t & 127;
    srow[rr][cc] = W0[(size_t)(r0 + rr) * F + cc];
  }
  __syncthreads();
  float acc[LROWS] = {0.f, 0.f, 0.f, 0.f};
  const float4* wv4 = (const float4*)(w_ih + (size_t)t * F);
#pragma unroll 4
  for (int k4 = 0; k4 < F / 4; k4++) {
    float4 w = wv4[k4];
#pragma unroll
    for (int i = 0; i < LROWS; i++) {
      float4 s = *(const float4*)&srow[i][k4 * 4];
      acc[i] = fmaf(s.x, w.x, fmaf(s.y, w.y, fmaf(s.z, w.z, fmaf(s.w, w.w, acc[i]))));
    }
  }
  float bias = b_ih[t] + b_hh[t];
#pragma unroll
  for (int i = 0; i < LROWS; i++) sg[i][t] = acc[i] + bias;
  __syncthreads();
  {
    int rr = t >> 7, c = t & 127;  // k = r0+rr, n = c
    float gi = sg[rr][c];
    float gg = sg[rr][c + 2 * F];
    float go = sg[rr][c + 3 * F];
    float si = 1.f / (1.f + expf(-gi));
    float so = 1.f / (1.f + expf(-go));
    float cc2 = si * tanhf(gg);
    float wval = so * tanhf(cc2);
    Wt[(size_t)c * F + (r0 + rr)] = (unsigned short)f2bfbits(wval);
  }
}

// ---------------- Kernel 3: in-degree count over targets (int atomics) ----
__global__ void deg_kernel(const int* __restrict__ col, int* __restrict__ deg,
                           int e) {
  int i = blockIdx.x * blockDim.x + threadIdx.x;
  if (i < e) atomicAdd(&deg[col[i]], 1);
}

// ---------------- Hierarchical exclusive scan (n <= 64*1024) --------------
__global__ __launch_bounds__(256) void scanA_kernel(const int* __restrict__ deg,
                                                    int* __restrict__ bsum,
                                                    int n) {
  int t = threadIdx.x, b = blockIdx.x;
  int base = b * 1024 + t * 4;
  int s = 0;
#pragma unroll
  for (int i = 0; i < 4; i++) {
    int idx = base + i;
    if (idx < n) s += deg[idx];
  }
#pragma unroll
  for (int off = 32; off > 0; off >>= 1) s += __shfl_down(s, off);
  __shared__ int wsum[4];
  if ((t & 63) == 0) wsum[t >> 6] = s;
  __syncthreads();
  if (t == 0) bsum[b] = wsum[0] + wsum[1] + wsum[2] + wsum[3];
}

__global__ __launch_bounds__(256) void scanC_kernel(
    const int* __restrict__ deg, const int* __restrict__ bsum,
    int* __restrict__ starts, int* __restrict__ cursor,
    float* __restrict__ dis, int n) {
  int t = threadIdx.x, b = blockIdx.x;
  int lane = t & 63, wave = t >> 6;
  __shared__ int wsum[4];
  __shared__ int bpre;
  if (wave == 0) {
    int v = (lane < b) ? bsum[lane] : 0;
#pragma unroll
    for (int off = 32; off > 0; off >>= 1) v += __shfl_down(v, off);
    if (lane == 0) bpre = v;
  }
  int base = b * 1024 + t * 4;
  int v[4];
  int s = 0;
#pragma unroll
  for (int i = 0; i < 4; i++) {
    int idx = base + i;
    v[i] = (idx < n) ? deg[idx] : 0;
    s += v[i];
  }
  int inc = s;
#pragma unroll
  for (int off = 1; off < 64; off <<= 1) {
    int u = __shfl_up(inc, off);
    if (lane >= off) inc += u;
  }
  if (lane == 63) wsum[wave] = inc;
  __syncthreads();
  int woff = 0;
  for (int w = 0; w < wave; w++) woff += wsum[w];
  int excl = inc - s + woff + bpre;
#pragma unroll
  for (int i = 0; i < 4; i++) {
    int idx = base + i;
    if (idx < n) {
      starts[idx] = excl;
      cursor[idx] = excl;
      dis[idx] = rsqrtf((float)(v[i] + 1));  // +1 self loop, always > 0
    }
    excl += v[i];
  }
}

// ---------------- Kernel 5: fill CSR buckets (by target) ----------------
__global__ void fill_kernel(const int* __restrict__ row,
                            const int* __restrict__ col,
                            int* __restrict__ cursor,
                            int* __restrict__ csr_src, int e) {
  int i = blockIdx.x * blockDim.x + threadIdx.x;
  if (i < e) {
    int c = col[i];
    int p = atomicAdd(&cursor[c], 1);
    csr_src[p] = row[i];
  }
}

// ---------------- Kernel 6: xw = x @ W  (bf16 MFMA, LDS-free) --------------
// 64 rows/block, 4 waves x 16 rows. A-frags read once from global fp32 x and
// packed to bf16 in registers; B-frags read from pre-transposed bf16 Wt
// (32 KB, L1/L2 resident). No LDS, no barriers, zero bank conflicts.
__global__ __launch_bounds__(256) void xw_mfma_kernel(
    const float* __restrict__ x, const unsigned short* __restrict__ Wt,
    unsigned short* __restrict__ xwb, int n) {
  int t = threadIdx.x;
  int w = t >> 6, l = t & 63;
  int q = l >> 4, m = l & 15;
  int m0 = blockIdx.x * 64 + w * 16;
  int arow = m0 + m;

  // A fragments: A[m = l&15][k = q*8 + j], kc chunks of 32
  bf16x8 a[4];
  const float4* xr4 = (const float4*)(x + (size_t)arow * F);
  bool rv = arow < n;
#pragma unroll
  for (int kc = 0; kc < 4; kc++) {
    uint4 pk = make_uint4(0u, 0u, 0u, 0u);
    if (rv) {
      float4 v0 = xr4[kc * 8 + q * 2 + 0];
      float4 v1 = xr4[kc * 8 + q * 2 + 1];
      pk.x = pack2bf(v0.x, v0.y);
      pk.y = pack2bf(v0.z, v0.w);
      pk.z = pack2bf(v1.x, v1.y);
      pk.w = pack2bf(v1.z, v1.w);
    }
    a[kc] = __builtin_bit_cast(bf16x8, pk);
  }

#pragma unroll
  for (int nc = 0; nc < 8; nc++) {
    f32x4 acc = {0.f, 0.f, 0.f, 0.f};
#pragma unroll
    for (int kc = 0; kc < 4; kc++) {
      // B[k][n]: lane holds n = l&15, k = kc*32 + q*8 + j ; Wt is [n][k]
      uint4 bu = *(const uint4*)(Wt + (size_t)(nc * 16 + m) * F + kc * 32 + q * 8);
      bf16x8 b = __builtin_bit_cast(bf16x8, bu);
      acc = __builtin_amdgcn_mfma_f32_16x16x32_bf16(a[kc], b, acc, 0, 0, 0);
    }
    // D[row = q*4 + r][col = l&15]
#pragma unroll
    for (int r = 0; r < 4; r++) {
      int gr = m0 + q * 4 + r;
      if (gr < n)
        xwb[(size_t)gr * F + nc * 16 + m] = (unsigned short)f2bfbits(acc[r]);
    }
  }
}

// ---------------- Kernel 7: pull aggregation + epilogue (fused, bf16 gather) --
__global__ __launch_bounds__(256) void agg_kernel(
    const int* __restrict__ starts, const int* __restrict__ deg,
    const int* __restrict__ csr_src, const float* __restrict__ dis,
    const unsigned int* __restrict__ xwb, const float* __restrict__ gcn_bias,
    const float* __restrict__ Wc, const float* __restrict__ bc,
    float* __restrict__ out, int n) {
  int wave = threadIdx.x >> 6;
  int lane = threadIdx.x & 63;
  int v = blockIdx.x * 4 + wave;
  if (v >= n) return;
  float dv = dis[v];
  float ax, ay;
  {
    unsigned int u = xwb[(size_t)v * 64 + lane];  // self loop
    float sl = dv * dv;
    ax = sl * __uint_as_float(u << 16);
    ay = sl * __uint_as_float(u & 0xffff0000u);
  }
  int b = starts[v];
  int eend = b + deg[v];
  int j = b;
  for (; j + 8 <= eend; j += 8) {
    int s[8];
    float nr[8];
    unsigned int u[8];
#pragma unroll
    for (int q = 0; q < 8; q++) s[q] = csr_src[j + q];
#pragma unroll
    for (int q = 0; q < 8; q++) nr[q] = dis[s[q]] * dv;
#pragma unroll
    for (int q = 0; q < 8; q++) u[q] = xwb[(size_t)s[q] * 64 + lane];
#pragma unroll
    for (int q = 0; q < 8; q++) {
      ax = fmaf(nr[q], __uint_as_float(u[q] << 16), ax);
      ay = fmaf(nr[q], __uint_as_float(u[q] & 0xffff0000u), ay);
    }
  }
  for (; j < eend; j++) {
    int s = csr_src[j];
    float nr = dis[s] * dv;
    unsigned int u = xwb[(size_t)s * 64 + lane];
    ax = fmaf(nr, __uint_as_float(u << 16), ax);
    ay = fmaf(nr, __uint_as_float(u & 0xffff0000u), ay);
  }
  int f0 = lane * 2;
  float h0 = fmaxf(ax + gcn_bias[f0], 0.f);
  float h1 = fmaxf(ay + gcn_bias[f0 + 1], 0.f);
  float a0 = h0 * Wc[f0] + h1 * Wc[f0 + 1];
  float a1 = h0 * Wc[F + f0] + h1 * Wc[F + f0 + 1];
#pragma unroll
  for (int off = 32; off > 0; off >>= 1) {
    a0 += __shfl_down(a0, off);
    a1 += __shfl_down(a1, off);
  }
  if (lane == 0) {
    out[(size_t)v * 2 + 0] = a0 + bc[0];
    out[(size_t)v * 2 + 1] = a1 + bc[1];
  }
}

extern "C" void kernel_launch(void* const* d_in, const int* in_sizes, int n_in,
                              void* d_out, int out_size, void* d_ws, size_t ws_size,
                              hipStream_t stream) {
  const float* x        = (const float*)d_in[0];
  const float* W0       = (const float*)d_in[1];
  const float* w_ih     = (const float*)d_in[2];
  // d_in[3] = w_hh unused (h0 = 0)
  const float* b_ih     = (const float*)d_in[4];
  const float* b_hh     = (const float*)d_in[5];
  const float* gcn_bias = (const float*)d_in[6];
  const float* Wc       = (const float*)d_in[7];
  const float* bc       = (const float*)d_in[8];
  const int*   ei       = (const int*)d_in[9];

  const int n = in_sizes[0] / F;   // 50000
  const int e = in_sizes[9] / 2;   // 600000
  const int* row = ei;
  const int* col = ei + e;

  // workspace layout
  char* wsb = (char*)d_ws;
  unsigned short* Wt   = (unsigned short*)wsb;  wsb += (size_t)F * F * 4;  // bf16 W^T (over-alloc ok)
  int*          deg    = (int*)wsb;             wsb += (size_t)n * 4;
  int*          starts = (int*)wsb;             wsb += (size_t)n * 4;
  int*          cursor = (int*)wsb;             wsb += (size_t)n * 4;
  float*        dis    = (float*)wsb;           wsb += (size_t)n * 4;
  int*          bsum   = (int*)wsb;             wsb += 64 * 4;
  int*          csr    = (int*)wsb;             wsb += (size_t)e * 4;
  unsigned short* xwb  = (unsigned short*)wsb;  // n*128 bf16

  const int scan_blocks = 64;  // covers 64*1024 = 65536 >= n

  // 1. zero degrees (async memset is graph-capturable)
  hipMemsetAsync(deg, 0, (size_t)n * sizeof(int), stream);

  // 2. LSTM weight evolution -> bf16 transposed Wt
  lstm_evolve_kernel<<<F / LROWS, 512, 0, stream>>>(W0, w_ih, b_ih, b_hh, Wt);

  // 3. in-degree over targets
  deg_kernel<<<(e + 255) / 256, 256, 0, stream>>>(col, deg, e);

  // 4. hierarchical exclusive scan + cursor + dis = rsqrt(deg+1)
  scanA_kernel<<<scan_blocks, 256, 0, stream>>>(deg, bsum, n);
  scanC_kernel<<<scan_blocks, 256, 0, stream>>>(deg, bsum, starts, cursor, dis, n);

  // 5. CSR bucket fill
  fill_kernel<<<(e + 255) / 256, 256, 0, stream>>>(row, col, cursor, csr, e);

  // 6. xw = x @ W (bf16 MFMA, fp32 accumulate, bf16 store)
  xw_mfma_kernel<<<(n + 63) / 64, 256, 0, stream>>>(x, Wt, xwb, n);

  // 7. fused pull-aggregation + bias + relu + classifier (bf16 gather)
  agg_kernel<<<(n + 3) / 4, 256, 0, stream>>>(starts, deg, csr, dis,
                                              (const unsigned int*)xwb,
                                              gcn_bias, Wc, bc,
                                              (float*)d_out, n);
}